// Round 1
// baseline (371.053 us; speedup 1.0000x reference)
//
#include <hip/hip_runtime.h>

typedef __attribute__((ext_vector_type(8))) short bf16x8;
typedef __attribute__((ext_vector_type(4))) float f32x4;
typedef unsigned short u16;

__device__ __forceinline__ u16 f2bf(float f) {
  union { float f; unsigned u; } v; v.f = f;
  unsigned r = v.u + 0x7fffu + ((v.u >> 16) & 1u);   // RNE
  return (u16)(r >> 16);
}
__device__ __forceinline__ float bf2f(u16 u) {
  union { unsigned u; float f; } v; v.u = ((unsigned)u) << 16;
  return v.f;
}
__device__ __forceinline__ void gload16(const void* g, void* l) {
  __builtin_amdgcn_global_load_lds((const __attribute__((address_space(1))) void*)g,
                                   (__attribute__((address_space(3))) void*)l, 16, 0, 0);
}

// ---------------- fp32 -> bf16 converter (4 elems/thread) ----------------
__global__ void sab_cvt_kernel(const float* __restrict__ src, u16* __restrict__ dst, int n4) {
  int i = blockIdx.x * blockDim.x + threadIdx.x;
  if (i >= n4) return;
  float4 f = reinterpret_cast<const float4*>(src)[i];
  ushort4 o; o.x = f2bf(f.x); o.y = f2bf(f.y); o.z = f2bf(f.z); o.w = f2bf(f.w);
  reinterpret_cast<ushort4*>(dst)[i] = o;
}

// ------------- window partition + convert: xw[r][c] = x[xrow(r)][c] -------------
__global__ void sab_xw_kernel(const float* __restrict__ x, u16* __restrict__ xw) {
  const int r = blockIdx.x;                 // 0..32767 (window-token row)
  const int w = r >> 8, tt = r & 255;
  const int b = w >> 4, h1 = (w >> 2) & 3, w1 = w & 3;
  const int i = tt >> 4, j = tt & 15;
  const long xrow = (long)b * 4096 + (h1 * 16 + i) * 64 + w1 * 16 + j;
  const float4* src = reinterpret_cast<const float4*>(x + xrow * 768);
  ushort4* dst = reinterpret_cast<ushort4*>(xw + (long)r * 768);
  const int c = threadIdx.x;                // 0..191, 192*4 = 768
  float4 f = src[c];
  ushort4 o; o.x = f2bf(f.x); o.y = f2bf(f.y); o.z = f2bf(f.z); o.w = f2bf(f.w);
  dst[c] = o;
}

// ---------------- GEMM: C[M,N] = A[M,K] * Bt[N,K]^T  (bf16 in, fp32 acc) ----------------
// EPI 0: store bf16 to outB (ldc = N).   EPI 1: store fp32 to outF with window-unpartition row permute + bias.
template<int EPI>
__global__ __launch_bounds__(256, 2)
void sab_gemm_kernel(const u16* __restrict__ A, const u16* __restrict__ Bt,
                     u16* __restrict__ outB, float* __restrict__ outF,
                     const float* __restrict__ bias, const int K, const int N)
{
  __shared__ __align__(16) u16 Ash[128 * 64];
  __shared__ __align__(16) u16 Bsh[128 * 64];
  const int tid = threadIdx.x;
  const int lane = tid & 63, wid = tid >> 6;
  const int wr = wid >> 1, wc = wid & 1;
  const int lr = lane & 15, lg = lane >> 4;
  const long m0 = (long)blockIdx.x * 128;
  const long n0 = (long)blockIdx.y * 128;

  const int srow = tid >> 3;                // 0..31
  const int scol = (tid & 7) * 8;           // 0..56
  const u16* Ag = A + (m0 + srow) * K + scol;
  const u16* Bg = Bt + (n0 + srow) * K + scol;
  u16* Al = Ash + wid * 512;                // wave-uniform base; HW adds lane*16B
  u16* Bl = Bsh + wid * 512;

  f32x4 acc[4][4];
#pragma unroll
  for (int a = 0; a < 4; ++a)
#pragma unroll
    for (int b = 0; b < 4; ++b) acc[a][b] = (f32x4){0.f, 0.f, 0.f, 0.f};

  for (int kt = 0; kt < K; kt += 64) {
#pragma unroll
    for (int i = 0; i < 4; ++i) {
      gload16(Ag + (long)i * 32 * K + kt, Al + i * 2048);
      gload16(Bg + (long)i * 32 * K + kt, Bl + i * 2048);
    }
    __syncthreads();
    bf16x8 af[4][2], bfr[4][2];
#pragma unroll
    for (int mt = 0; mt < 4; ++mt)
#pragma unroll
      for (int kc = 0; kc < 2; ++kc)
        af[mt][kc] = *reinterpret_cast<const bf16x8*>(&Ash[(wr * 64 + mt * 16 + lr) * 64 + kc * 32 + lg * 8]);
#pragma unroll
    for (int nt = 0; nt < 4; ++nt)
#pragma unroll
      for (int kc = 0; kc < 2; ++kc)
        bfr[nt][kc] = *reinterpret_cast<const bf16x8*>(&Bsh[(wc * 64 + nt * 16 + lr) * 64 + kc * 32 + lg * 8]);
#pragma unroll
    for (int kc = 0; kc < 2; ++kc)
#pragma unroll
      for (int mt = 0; mt < 4; ++mt)
#pragma unroll
        for (int nt = 0; nt < 4; ++nt)
          acc[mt][nt] = __builtin_amdgcn_mfma_f32_16x16x32_bf16(af[mt][kc], bfr[nt][kc], acc[mt][nt], 0, 0, 0);
    __syncthreads();
  }

#pragma unroll
  for (int mt = 0; mt < 4; ++mt)
#pragma unroll
    for (int nt = 0; nt < 4; ++nt) {
      const long col = n0 + wc * 64 + nt * 16 + lr;
      float bv = 0.f;
      if (EPI == 1) bv = bias[col];
#pragma unroll
      for (int r = 0; r < 4; ++r) {
        const long row = m0 + wr * 64 + mt * 16 + lg * 4 + r;
        if (EPI == 0) {
          outB[row * N + col] = f2bf(acc[mt][nt][r]);
        } else {
          const int rr = (int)row;
          const int w = rr >> 8, tt = rr & 255;
          const long xrow = (long)(w >> 4) * 4096 + (((w >> 2) & 3) * 16 + (tt >> 4)) * 64 + (w & 3) * 16 + (tt & 15);
          outF[xrow * 768 + col] = acc[mt][nt][r] + bv;
        }
      }
    }
}

// ---------------- fused windowed attention: one block per (window, head) ----------------
// qkv layout: [32768 rows][2304]: q at col 0, k at 768, v at 1536; head h owns cols h*64..h*64+63.
__global__ __launch_bounds__(256, 2)
void sab_attn_kernel(const u16* __restrict__ qkv, const float* __restrict__ rph,
                     const float* __restrict__ rpw, u16* __restrict__ oatt)
{
  __shared__ __align__(16) u16 relh_s[256 * 16];     // bias_h[x][k]  (bf16)
  __shared__ __align__(16) u16 relw_s[256 * 16];     // bias_w[x][l]
  __shared__ __align__(16) u16 VT[64 * 80];          // V^T [d][key(+pad)] for current 64-key block
  __shared__ __align__(16) u16 Sbuf[4][64 * 72];     // per-wave P tile (64 q-rows x 64 keys, pad 72)

  const int blk = blockIdx.x;
  const int w = blk / 12, h = blk % 12;
  const long qbase = (long)w * 256;
  const int tid = threadIdx.x, lane = tid & 63, wid = tid >> 6;
  const int lr = lane & 15, lg = lane >> 4;

  const u16* Qp = qkv + (long)h * 64;
  const u16* Kp = qkv + 768 + (long)h * 64;
  const u16* Vp = qkv + 1536 + (long)h * 64;

  // ---- phase 0: decomposed rel-pos tables via MFMA ----
  // rel_h[x=(i,j)][k] = dot(q_x, rel_pos_h[i-k+15]); wave wid handles i = wid*4+ii
#pragma unroll
  for (int ii = 0; ii < 4; ++ii) {
    const int i = wid * 4 + ii;
    f32x4 acc = (f32x4){0.f, 0.f, 0.f, 0.f};
#pragma unroll
    for (int kc = 0; kc < 2; ++kc) {
      bf16x8 a = *reinterpret_cast<const bf16x8*>(&Qp[(qbase + i * 16 + lr) * 2304 + kc * 32 + lg * 8]);
      const float* bp = rph + (i - lr + 15) * 64 + kc * 32 + lg * 8;
      bf16x8 b;
#pragma unroll
      for (int e = 0; e < 8; ++e) b[e] = (short)f2bf(bp[e]);
      acc = __builtin_amdgcn_mfma_f32_16x16x32_bf16(a, b, acc, 0, 0, 0);
    }
#pragma unroll
    for (int r = 0; r < 4; ++r)
      relh_s[(i * 16 + lg * 4 + r) * 16 + lr] = f2bf(acc[r]);
  }
  // rel_w[x=(i,j)][l] = dot(q_x, rel_pos_w[j-l+15]); wave handles j = wid*4+jj
#pragma unroll
  for (int jj = 0; jj < 4; ++jj) {
    const int j = wid * 4 + jj;
    f32x4 acc = (f32x4){0.f, 0.f, 0.f, 0.f};
#pragma unroll
    for (int kc = 0; kc < 2; ++kc) {
      bf16x8 a = *reinterpret_cast<const bf16x8*>(&Qp[(qbase + lr * 16 + j) * 2304 + kc * 32 + lg * 8]);
      const float* bp = rpw + (j - lr + 15) * 64 + kc * 32 + lg * 8;
      bf16x8 b;
#pragma unroll
      for (int e = 0; e < 8; ++e) b[e] = (short)f2bf(bp[e]);
      acc = __builtin_amdgcn_mfma_f32_16x16x32_bf16(a, b, acc, 0, 0, 0);
    }
#pragma unroll
    for (int r = 0; r < 4; ++r)
      relw_s[((lg * 4 + r) * 16 + j) * 16 + lr] = f2bf(acc[r]);
  }
  __syncthreads();

  // ---- Q fragments (wave owns q-rows wid*64 .. wid*64+63) ----
  bf16x8 qa[4][2];
#pragma unroll
  for (int mt = 0; mt < 4; ++mt)
#pragma unroll
    for (int kc = 0; kc < 2; ++kc)
      qa[mt][kc] = *reinterpret_cast<const bf16x8*>(&Qp[(qbase + wid * 64 + mt * 16 + lr) * 2304 + kc * 32 + lg * 8]);

  float rw[4][4];
#pragma unroll
  for (int mt = 0; mt < 4; ++mt)
#pragma unroll
    for (int r = 0; r < 4; ++r)
      rw[mt][r] = bf2f(relw_s[(wid * 64 + mt * 16 + lg * 4 + r) * 16 + lr]);

  float mrun[4][4], lrun[4][4];
  f32x4 oacc[4][4];
#pragma unroll
  for (int mt = 0; mt < 4; ++mt)
#pragma unroll
    for (int r = 0; r < 4; ++r) { mrun[mt][r] = -1e30f; lrun[mt][r] = 0.f; }
#pragma unroll
  for (int mt = 0; mt < 4; ++mt)
#pragma unroll
    for (int nt = 0; nt < 4; ++nt) oacc[mt][nt] = (f32x4){0.f, 0.f, 0.f, 0.f};

  u16* sb = &Sbuf[wid][0];

  for (int kb = 0; kb < 4; ++kb) {
    __syncthreads();                       // protect VT from previous iteration's readers
    {                                      // cooperative V^T staging (64 keys x 64 d)
      const int key = tid >> 2, d0 = (tid & 3) * 16;
      const u16* vs = &Vp[(qbase + kb * 64 + key) * 2304 + d0];
      bf16x8 v0 = *reinterpret_cast<const bf16x8*>(vs);
      bf16x8 v1 = *reinterpret_cast<const bf16x8*>(vs + 8);
#pragma unroll
      for (int e = 0; e < 8; ++e) VT[(d0 + e) * 80 + key] = (u16)v0[e];
#pragma unroll
      for (int e = 0; e < 8; ++e) VT[(d0 + 8 + e) * 80 + key] = (u16)v1[e];
    }
    __syncthreads();

    // ---- S = Q K^T for this 64-key block ----
    bf16x8 kf[4][2];
#pragma unroll
    for (int nt = 0; nt < 4; ++nt)
#pragma unroll
      for (int kc = 0; kc < 2; ++kc)
        kf[nt][kc] = *reinterpret_cast<const bf16x8*>(&Kp[(qbase + kb * 64 + nt * 16 + lr) * 2304 + kc * 32 + lg * 8]);
    f32x4 s[4][4];
#pragma unroll
    for (int mt = 0; mt < 4; ++mt)
#pragma unroll
      for (int nt = 0; nt < 4; ++nt) {
        f32x4 t = (f32x4){0.f, 0.f, 0.f, 0.f};
#pragma unroll
        for (int kc = 0; kc < 2; ++kc)
          t = __builtin_amdgcn_mfma_f32_16x16x32_bf16(qa[mt][kc], kf[nt][kc], t, 0, 0, 0);
        s[mt][nt] = t;
      }

    // ---- bias + online softmax (row = mt*16 + lg*4 + r, col = nt*16 + lr) ----
#pragma unroll
    for (int mt = 0; mt < 4; ++mt) {
      float sv[4][4];
#pragma unroll
      for (int r = 0; r < 4; ++r) {
        const int x = wid * 64 + mt * 16 + lg * 4 + r;
#pragma unroll
        for (int nt = 0; nt < 4; ++nt)
          sv[r][nt] = s[mt][nt][r] * 0.125f + bf2f(relh_s[x * 16 + kb * 4 + nt]) + rw[mt][r];
      }
#pragma unroll
      for (int r = 0; r < 4; ++r) {
        float rmax = fmaxf(fmaxf(sv[r][0], sv[r][1]), fmaxf(sv[r][2], sv[r][3]));
        rmax = fmaxf(rmax, __shfl_xor(rmax, 1));
        rmax = fmaxf(rmax, __shfl_xor(rmax, 2));
        rmax = fmaxf(rmax, __shfl_xor(rmax, 4));
        rmax = fmaxf(rmax, __shfl_xor(rmax, 8));
        const float mnew = fmaxf(mrun[mt][r], rmax);
        const float sf = __expf(mrun[mt][r] - mnew);
        mrun[mt][r] = mnew;
        float rsum = 0.f;
#pragma unroll
        for (int nt = 0; nt < 4; ++nt) { const float p = __expf(sv[r][nt] - mnew); sv[r][nt] = p; rsum += p; }
        rsum += __shfl_xor(rsum, 1);
        rsum += __shfl_xor(rsum, 2);
        rsum += __shfl_xor(rsum, 4);
        rsum += __shfl_xor(rsum, 8);
        lrun[mt][r] = lrun[mt][r] * sf + rsum;
#pragma unroll
        for (int nt = 0; nt < 4; ++nt) oacc[mt][nt][r] *= sf;
        const int rowl = mt * 16 + lg * 4 + r;
#pragma unroll
        for (int nt = 0; nt < 4; ++nt) sb[rowl * 72 + nt * 16 + lr] = f2bf(sv[r][nt]);
      }
    }
    __syncthreads();                        // P visible (and VT stable) before PV

    // ---- O += P V ----
#pragma unroll
    for (int kc = 0; kc < 2; ++kc) {
      bf16x8 vf[4];
#pragma unroll
      for (int nt = 0; nt < 4; ++nt)
        vf[nt] = *reinterpret_cast<const bf16x8*>(&VT[(nt * 16 + lr) * 80 + kc * 32 + lg * 8]);
#pragma unroll
      for (int mt = 0; mt < 4; ++mt) {
        bf16x8 pa = *reinterpret_cast<const bf16x8*>(&sb[(mt * 16 + lr) * 72 + kc * 32 + lg * 8]);
#pragma unroll
        for (int nt = 0; nt < 4; ++nt)
          oacc[mt][nt] = __builtin_amdgcn_mfma_f32_16x16x32_bf16(pa, vf[nt], oacc[mt][nt], 0, 0, 0);
      }
    }
  }

  // ---- epilogue: O / l -> oatt[row][h*64+d] (bf16) ----
#pragma unroll
  for (int mt = 0; mt < 4; ++mt)
#pragma unroll
    for (int r = 0; r < 4; ++r) {
      const float inv = 1.f / lrun[mt][r];
      const long row = qbase + wid * 64 + mt * 16 + lg * 4 + r;
#pragma unroll
      for (int nt = 0; nt < 4; ++nt)
        oatt[row * 768 + h * 64 + nt * 16 + lr] = f2bf(oacc[mt][nt][r] * inv);
    }
}

extern "C" void kernel_launch(void* const* d_in, const int* in_sizes, int n_in,
                              void* d_out, int out_size, void* d_ws, size_t ws_size,
                              hipStream_t stream) {
  (void)in_sizes; (void)n_in; (void)out_size; (void)ws_size;
  const float* x     = (const float*)d_in[0];
  const float* w_qkv = (const float*)d_in[1];
  const float* w_out = (const float*)d_in[2];
  const float* b_out = (const float*)d_in[3];
  const float* rph   = (const float*)d_in[4];
  const float* rpw   = (const float*)d_in[5];
  float* out = (float*)d_out;

  char* ws = (char*)d_ws;
  u16* qkv   = (u16*)ws;                              // 32768*2304 bf16 = 151.0 MB
  u16* xw    = (u16*)(ws + 150994944L);               // 32768*768  bf16 =  50.3 MB (reused as oatt)
  u16* wqkvb = (u16*)(ws + 201326592L);               // 2304*768 bf16
  u16* woutb = (u16*)(ws + 204865536L);               //  768*768 bf16; total 206.0 MB
  u16* oatt  = xw;                                    // xw is dead after gemm1

  sab_cvt_kernel<<<dim3(1728), dim3(256), 0, stream>>>(w_qkv, wqkvb, 442368);
  sab_cvt_kernel<<<dim3(576), dim3(256), 0, stream>>>(w_out, woutb, 147456);
  sab_xw_kernel<<<dim3(32768), dim3(192), 0, stream>>>(x, xw);
  sab_gemm_kernel<0><<<dim3(256, 18), dim3(256), 0, stream>>>(xw, wqkvb, qkv, nullptr, nullptr, 768, 2304);
  sab_attn_kernel<<<dim3(1536), dim3(256), 0, stream>>>(qkv, rph, rpw, oatt);
  sab_gemm_kernel<1><<<dim3(256, 6), dim3(256), 0, stream>>>(oatt, woutb, nullptr, out, b_out, 768, 768);
}

// Round 2
// 366.381 us; speedup vs baseline: 1.0128x; 1.0128x over previous
//
#include <hip/hip_runtime.h>

typedef __attribute__((ext_vector_type(8))) short bf16x8;
typedef __attribute__((ext_vector_type(4))) float f32x4;
typedef unsigned short u16;

__device__ __forceinline__ u16 f2bf(float f) {
  union { float f; unsigned u; } v; v.f = f;
  unsigned r = v.u + 0x7fffu + ((v.u >> 16) & 1u);   // RNE
  return (u16)(r >> 16);
}
__device__ __forceinline__ float bf2f(u16 u) {
  union { unsigned u; float f; } v; v.u = ((unsigned)u) << 16;
  return v.f;
}
__device__ __forceinline__ void gload16(const void* g, void* l) {
  __builtin_amdgcn_global_load_lds((const __attribute__((address_space(1))) void*)g,
                                   (__attribute__((address_space(3))) void*)l, 16, 0, 0);
}

// ---------------- fp32 -> bf16 converter (4 elems/thread) ----------------
__global__ void sab_cvt_kernel(const float* __restrict__ src, u16* __restrict__ dst, int n4) {
  int i = blockIdx.x * blockDim.x + threadIdx.x;
  if (i >= n4) return;
  float4 f = reinterpret_cast<const float4*>(src)[i];
  ushort4 o; o.x = f2bf(f.x); o.y = f2bf(f.y); o.z = f2bf(f.z); o.w = f2bf(f.w);
  reinterpret_cast<ushort4*>(dst)[i] = o;
}

// ------------- window partition + convert: xw[r][c] = x[xrow(r)][c] -------------
__global__ void sab_xw_kernel(const float* __restrict__ x, u16* __restrict__ xw) {
  const int r = blockIdx.x;                 // 0..32767 (window-token row)
  const int w = r >> 8, tt = r & 255;
  const int b = w >> 4, h1 = (w >> 2) & 3, w1 = w & 3;
  const int i = tt >> 4, j = tt & 15;
  const long xrow = (long)b * 4096 + (h1 * 16 + i) * 64 + w1 * 16 + j;
  const float4* src = reinterpret_cast<const float4*>(x + xrow * 768);
  ushort4* dst = reinterpret_cast<ushort4*>(xw + (long)r * 768);
  const int c = threadIdx.x;                // 0..191, 192*4 = 768
  float4 f = src[c];
  ushort4 o; o.x = f2bf(f.x); o.y = f2bf(f.y); o.z = f2bf(f.z); o.w = f2bf(f.w);
  dst[c] = o;
}

// ---------------- GEMM: C[M,N] = A[M,K] * Bt[N,K]^T  (bf16 in, fp32 acc) ----------------
// EPI 0 (qkv proj): cols <1536 -> bf16 row-major into outB (ld 1536);
//                   cols >=1536 (v) -> TRANSPOSED into vTp[col-1536][row] (ld 32768), 4-row packed stores.
// EPI 1 (out proj): fp32 to outF with window-unpartition row permute + bias.
template<int EPI>
__global__ __launch_bounds__(256, 4)
void sab_gemm_kernel(const u16* __restrict__ A, const u16* __restrict__ Bt,
                     u16* __restrict__ outB, u16* __restrict__ vTp,
                     float* __restrict__ outF, const float* __restrict__ bias,
                     const int K, const int N)
{
  __shared__ __align__(16) u16 Ash[128 * 64];
  __shared__ __align__(16) u16 Bsh[128 * 64];
  const int tid = threadIdx.x;
  const int lane = tid & 63, wid = tid >> 6;
  const int wr = wid >> 1, wc = wid & 1;
  const int lr = lane & 15, lg = lane >> 4;
  const long m0 = (long)blockIdx.x * 128;
  const long n0 = (long)blockIdx.y * 128;

  const int srow = tid >> 3;                // 0..31
  const int scol = (tid & 7) * 8;           // 0..56
  const u16* Ag = A + (m0 + srow) * K + scol;
  const u16* Bg = Bt + (n0 + srow) * K + scol;
  u16* Al = Ash + wid * 512;                // wave-uniform base; HW adds lane*16B
  u16* Bl = Bsh + wid * 512;

  f32x4 acc[4][4];
#pragma unroll
  for (int a = 0; a < 4; ++a)
#pragma unroll
    for (int b = 0; b < 4; ++b) acc[a][b] = (f32x4){0.f, 0.f, 0.f, 0.f};

  for (int kt = 0; kt < K; kt += 64) {
#pragma unroll
    for (int i = 0; i < 4; ++i) {
      gload16(Ag + (long)i * 32 * K + kt, Al + i * 2048);
      gload16(Bg + (long)i * 32 * K + kt, Bl + i * 2048);
    }
    __syncthreads();
    bf16x8 af[4][2], bfr[4][2];
#pragma unroll
    for (int mt = 0; mt < 4; ++mt)
#pragma unroll
      for (int kc = 0; kc < 2; ++kc)
        af[mt][kc] = *reinterpret_cast<const bf16x8*>(&Ash[(wr * 64 + mt * 16 + lr) * 64 + kc * 32 + lg * 8]);
#pragma unroll
    for (int nt = 0; nt < 4; ++nt)
#pragma unroll
      for (int kc = 0; kc < 2; ++kc)
        bfr[nt][kc] = *reinterpret_cast<const bf16x8*>(&Bsh[(wc * 64 + nt * 16 + lr) * 64 + kc * 32 + lg * 8]);
#pragma unroll
    for (int kc = 0; kc < 2; ++kc)
#pragma unroll
      for (int mt = 0; mt < 4; ++mt)
#pragma unroll
        for (int nt = 0; nt < 4; ++nt)
          acc[mt][nt] = __builtin_amdgcn_mfma_f32_16x16x32_bf16(af[mt][kc], bfr[nt][kc], acc[mt][nt], 0, 0, 0);
    __syncthreads();
  }

#pragma unroll
  for (int mt = 0; mt < 4; ++mt)
#pragma unroll
    for (int nt = 0; nt < 4; ++nt) {
      const long col = n0 + wc * 64 + nt * 16 + lr;
      if (EPI == 0) {
        const long row0 = m0 + wr * 64 + mt * 16 + lg * 4;
        if (n0 < 1536) {                    // q/k region: row-major, ld 1536
#pragma unroll
          for (int r = 0; r < 4; ++r)
            outB[(row0 + r) * 1536 + col] = f2bf(acc[mt][nt][r]);
        } else {                            // v region: transposed, packed 4-row store
          ushort4 o;
          o.x = f2bf(acc[mt][nt][0]); o.y = f2bf(acc[mt][nt][1]);
          o.z = f2bf(acc[mt][nt][2]); o.w = f2bf(acc[mt][nt][3]);
          *reinterpret_cast<ushort4*>(&vTp[(col - 1536) * 32768L + row0]) = o;
        }
      } else {
        const float bv = bias[col];
#pragma unroll
        for (int r = 0; r < 4; ++r) {
          const int rr = (int)(m0 + wr * 64 + mt * 16 + lg * 4 + r);
          const int w = rr >> 8, tt = rr & 255;
          const long xrow = (long)(w >> 4) * 4096 + (((w >> 2) & 3) * 16 + (tt >> 4)) * 64 + (w & 3) * 16 + (tt & 15);
          outF[xrow * 768 + col] = acc[mt][nt][r] + bv;
        }
      }
    }
}

// ---------------- fused windowed attention: one block per (window, head) ----------------
// qk layout: [32768 rows][1536]: q at col 0, k at 768; head h owns cols h*64..h*64+63.
// vT layout: [768][32768]: vT[h*64+d][window_row] — PV B-fragments load contiguous 16B.
__global__ __launch_bounds__(256, 2)
void sab_attn_kernel(const u16* __restrict__ qk, const u16* __restrict__ vT,
                     const float* __restrict__ rph, const float* __restrict__ rpw,
                     u16* __restrict__ oatt)
{
  __shared__ __align__(16) u16 relh_s[256 * 16];     // bias_h[x][k]  (bf16)
  __shared__ __align__(16) u16 relw_s[256 * 16];     // bias_w[x][l]
  __shared__ __align__(16) u16 Sbuf[4][64 * 72];     // per-wave private P tile (no barrier needed)

  const int blk0 = blockIdx.x;
  const int blk = (blk0 & 7) * 192 + (blk0 >> 3);    // bijective XCD swizzle (1536 = 8*192)
  const int w = blk / 12, h = blk % 12;
  const long qbase = (long)w * 256;
  const int tid = threadIdx.x, lane = tid & 63, wid = tid >> 6;
  const int lr = lane & 15, lg = lane >> 4;

  const u16* Qp = qk + (long)h * 64;
  const u16* Kp = qk + 768 + (long)h * 64;
  const u16* Vt = vT + (long)h * 64 * 32768 + w * 256;   // Vt[d*32768 + key_local]

  // ---- phase 0: decomposed rel-pos tables via MFMA ----
#pragma unroll
  for (int ii = 0; ii < 4; ++ii) {
    const int i = wid * 4 + ii;
    f32x4 acc = (f32x4){0.f, 0.f, 0.f, 0.f};
#pragma unroll
    for (int kc = 0; kc < 2; ++kc) {
      bf16x8 a = *reinterpret_cast<const bf16x8*>(&Qp[(qbase + i * 16 + lr) * 1536 + kc * 32 + lg * 8]);
      const float* bp = rph + (i - lr + 15) * 64 + kc * 32 + lg * 8;
      bf16x8 b;
#pragma unroll
      for (int e = 0; e < 8; ++e) b[e] = (short)f2bf(bp[e]);
      acc = __builtin_amdgcn_mfma_f32_16x16x32_bf16(a, b, acc, 0, 0, 0);
    }
#pragma unroll
    for (int r = 0; r < 4; ++r)
      relh_s[(i * 16 + lg * 4 + r) * 16 + lr] = f2bf(acc[r]);
  }
#pragma unroll
  for (int jj = 0; jj < 4; ++jj) {
    const int j = wid * 4 + jj;
    f32x4 acc = (f32x4){0.f, 0.f, 0.f, 0.f};
#pragma unroll
    for (int kc = 0; kc < 2; ++kc) {
      bf16x8 a = *reinterpret_cast<const bf16x8*>(&Qp[(qbase + lr * 16 + j) * 1536 + kc * 32 + lg * 8]);
      const float* bp = rpw + (j - lr + 15) * 64 + kc * 32 + lg * 8;
      bf16x8 b;
#pragma unroll
      for (int e = 0; e < 8; ++e) b[e] = (short)f2bf(bp[e]);
      acc = __builtin_amdgcn_mfma_f32_16x16x32_bf16(a, b, acc, 0, 0, 0);
    }
#pragma unroll
    for (int r = 0; r < 4; ++r)
      relw_s[((lg * 4 + r) * 16 + j) * 16 + lr] = f2bf(acc[r]);
  }
  __syncthreads();                          // the ONLY block-wide barrier

  // ---- Q fragments (wave owns q-rows wid*64 .. wid*64+63) ----
  bf16x8 qa[4][2];
#pragma unroll
  for (int mt = 0; mt < 4; ++mt)
#pragma unroll
    for (int kc = 0; kc < 2; ++kc)
      qa[mt][kc] = *reinterpret_cast<const bf16x8*>(&Qp[(qbase + wid * 64 + mt * 16 + lr) * 1536 + kc * 32 + lg * 8]);

  float rw[4][4];
#pragma unroll
  for (int mt = 0; mt < 4; ++mt)
#pragma unroll
    for (int r = 0; r < 4; ++r)
      rw[mt][r] = bf2f(relw_s[(wid * 64 + mt * 16 + lg * 4 + r) * 16 + lr]);

  float mrun[4][4], lrun[4][4];
  f32x4 oacc[4][4];
#pragma unroll
  for (int mt = 0; mt < 4; ++mt)
#pragma unroll
    for (int r = 0; r < 4; ++r) { mrun[mt][r] = -1e30f; lrun[mt][r] = 0.f; }
#pragma unroll
  for (int mt = 0; mt < 4; ++mt)
#pragma unroll
    for (int nt = 0; nt < 4; ++nt) oacc[mt][nt] = (f32x4){0.f, 0.f, 0.f, 0.f};

  u16* sb = &Sbuf[wid][0];

  for (int kb = 0; kb < 4; ++kb) {
    // ---- K fragments (global, L2-resident) + V fragments issued early ----
    bf16x8 kf[4][2], vf[4][2];
#pragma unroll
    for (int nt = 0; nt < 4; ++nt)
#pragma unroll
      for (int kc = 0; kc < 2; ++kc) {
        kf[nt][kc] = *reinterpret_cast<const bf16x8*>(&Kp[(qbase + kb * 64 + nt * 16 + lr) * 1536 + kc * 32 + lg * 8]);
        vf[nt][kc] = *reinterpret_cast<const bf16x8*>(&Vt[(nt * 16 + lr) * 32768L + kb * 64 + kc * 32 + lg * 8]);
      }

    // ---- S = Q K^T, bias, online softmax, P -> per-wave LDS (per mt to limit VGPR) ----
#pragma unroll
    for (int mt = 0; mt < 4; ++mt) {
      f32x4 sn[4];
#pragma unroll
      for (int nt = 0; nt < 4; ++nt) {
        f32x4 t = (f32x4){0.f, 0.f, 0.f, 0.f};
#pragma unroll
        for (int kc = 0; kc < 2; ++kc)
          t = __builtin_amdgcn_mfma_f32_16x16x32_bf16(qa[mt][kc], kf[nt][kc], t, 0, 0, 0);
        sn[nt] = t;
      }
#pragma unroll
      for (int r = 0; r < 4; ++r) {
        const int x = wid * 64 + mt * 16 + lg * 4 + r;
        float sv[4];
#pragma unroll
        for (int nt = 0; nt < 4; ++nt)
          sv[nt] = sn[nt][r] * 0.125f + bf2f(relh_s[x * 16 + kb * 4 + nt]) + rw[mt][r];
        float rmax = fmaxf(fmaxf(sv[0], sv[1]), fmaxf(sv[2], sv[3]));
        rmax = fmaxf(rmax, __shfl_xor(rmax, 1));
        rmax = fmaxf(rmax, __shfl_xor(rmax, 2));
        rmax = fmaxf(rmax, __shfl_xor(rmax, 4));
        rmax = fmaxf(rmax, __shfl_xor(rmax, 8));
        const float mnew = fmaxf(mrun[mt][r], rmax);
        const float sf = __expf(mrun[mt][r] - mnew);
        mrun[mt][r] = mnew;
        float rsum = 0.f;
#pragma unroll
        for (int nt = 0; nt < 4; ++nt) { const float p = __expf(sv[nt] - mnew); sv[nt] = p; rsum += p; }
        rsum += __shfl_xor(rsum, 1);
        rsum += __shfl_xor(rsum, 2);
        rsum += __shfl_xor(rsum, 4);
        rsum += __shfl_xor(rsum, 8);
        lrun[mt][r] = lrun[mt][r] * sf + rsum;
#pragma unroll
        for (int nt = 0; nt < 4; ++nt) oacc[mt][nt][r] *= sf;
        const int rowl = mt * 16 + lg * 4 + r;
#pragma unroll
        for (int nt = 0; nt < 4; ++nt) sb[rowl * 72 + nt * 16 + lr] = f2bf(sv[nt]);
      }
    }
    // same-wave LDS write->read: compiler inserts lgkmcnt, no barrier needed

    // ---- O += P V (B-fragments direct from vT) ----
#pragma unroll
    for (int kc = 0; kc < 2; ++kc)
#pragma unroll
      for (int mt = 0; mt < 4; ++mt) {
        bf16x8 pa = *reinterpret_cast<const bf16x8*>(&sb[(mt * 16 + lr) * 72 + kc * 32 + lg * 8]);
#pragma unroll
        for (int nt = 0; nt < 4; ++nt)
          oacc[mt][nt] = __builtin_amdgcn_mfma_f32_16x16x32_bf16(pa, vf[nt][kc], oacc[mt][nt], 0, 0, 0);
      }
  }

  // ---- epilogue: O / l -> oatt[row][h*64+d] (bf16) ----
#pragma unroll
  for (int mt = 0; mt < 4; ++mt)
#pragma unroll
    for (int r = 0; r < 4; ++r) {
      const float inv = 1.f / lrun[mt][r];
      const long row = qbase + wid * 64 + mt * 16 + lg * 4 + r;
#pragma unroll
      for (int nt = 0; nt < 4; ++nt)
        oatt[row * 768 + h * 64 + nt * 16 + lr] = f2bf(oacc[mt][nt][r] * inv);
    }
}

extern "C" void kernel_launch(void* const* d_in, const int* in_sizes, int n_in,
                              void* d_out, int out_size, void* d_ws, size_t ws_size,
                              hipStream_t stream) {
  (void)in_sizes; (void)n_in; (void)out_size; (void)ws_size;
  const float* x     = (const float*)d_in[0];
  const float* w_qkv = (const float*)d_in[1];
  const float* w_out = (const float*)d_in[2];
  const float* b_out = (const float*)d_in[3];
  const float* rph   = (const float*)d_in[4];
  const float* rpw   = (const float*)d_in[5];
  float* out = (float*)d_out;

  char* ws = (char*)d_ws;
  u16* qk    = (u16*)ws;                              // 32768*1536 bf16 = 100.7 MB (q,k row-major)
  u16* vT    = (u16*)(ws + 100663296L);               // 768*32768  bf16 =  50.3 MB (v transposed)
  u16* xw    = (u16*)(ws + 150994944L);               // 32768*768  bf16 =  50.3 MB (reused as oatt)
  u16* wqkvb = (u16*)(ws + 201326592L);               // 2304*768 bf16
  u16* woutb = (u16*)(ws + 204865536L);               //  768*768 bf16; total 206,045,184 B (same as R1)
  u16* oatt  = xw;                                    // xw is dead after gemm1

  sab_cvt_kernel<<<dim3(1728), dim3(256), 0, stream>>>(w_qkv, wqkvb, 442368);
  sab_cvt_kernel<<<dim3(576), dim3(256), 0, stream>>>(w_out, woutb, 147456);
  sab_xw_kernel<<<dim3(32768), dim3(192), 0, stream>>>(x, xw);
  sab_gemm_kernel<0><<<dim3(256, 18), dim3(256), 0, stream>>>(xw, wqkvb, qk, vT, nullptr, nullptr, 768, 2304);
  sab_attn_kernel<<<dim3(1536), dim3(256), 0, stream>>>(qk, vT, rph, rpw, oatt);
  sab_gemm_kernel<1><<<dim3(256, 6), dim3(256), 0, stream>>>(oatt, woutb, nullptr, nullptr, out, b_out, 768, 768);
}